// Round 7
// baseline (195.289 us; speedup 1.0000x reference)
//
#include <hip/hip_runtime.h>

#define B_   32
#define C_   64
#define T_   300
#define J_   25
#define K9   9
constexpr int PLANE = T_ * J_;           // 7500
constexpr int BCTJ  = B_ * C_ * PLANE;   // 15,360,000
constexpr float BN_EPS = 1e-5f;
constexpr float BN_N   = (float)(B_ * T_ * J_);  // 240000

typedef __attribute__((ext_vector_type(8))) short bf16x8;
typedef __attribute__((ext_vector_type(4))) float f32x4;
typedef __attribute__((ext_vector_type(8))) unsigned short u16x8;
typedef __attribute__((ext_vector_type(4))) unsigned short u16x4;

__device__ inline unsigned short f2bf(float f) {
  unsigned u = __float_as_uint(f);
  unsigned r = (u + 0x7FFF + ((u >> 16) & 1)) >> 16;
  return (unsigned short)r;
}
__device__ inline float bf2f(unsigned short h) {
  return __uint_as_float(((unsigned)h) << 16);
}

// ---------------------------------------------------------------------------
// K0: weight prep (unchanged).
__global__ __launch_bounds__(256) void prep_kernel(const float* __restrict__ tw,
                                                   const float* __restrict__ gw,
                                                   const float* __restrict__ A,
                                                   unsigned short* __restrict__ Wb,
                                                   unsigned short* __restrict__ Gb,
                                                   unsigned short* __restrict__ AdT) {
  int idx = blockIdx.x * 256 + threadIdx.x;
  if (idx < C_ * C_ * K9) {
    int o = idx / (C_ * K9);
    int rem = idx % (C_ * K9);
    int c = rem / K9, kt = rem % K9;
    Wb[kt * (C_ * C_) + o * C_ + c] = f2bf(tw[idx]);
  } else if (idx < C_ * C_ * K9 + C_ * C_) {
    int i = idx - C_ * C_ * K9;
    Gb[i] = f2bf(gw[i]);
  } else if (idx < C_ * C_ * K9 + C_ * C_ + 256 * 256) {
    int i = idx - (C_ * C_ * K9 + C_ * C_);
    int n = i >> 8, m = i & 255;
    float v = 0.f;
    if (n < 250 && m < 250) {
      if (n / 25 == m / 25) v = A[(m % 25) * 25 + (n % 25)];
    }
    AdT[i] = f2bf(v);
  }
}

// ---------------------------------------------------------------------------
// K1: GCN, 512 threads (8 waves x 32-col tiles). Fused BN1 partial stats.
//  Output y1T as bf16 [b][row][c].
constexpr int TTG = 10;
__global__ __launch_bounds__(512) void gcn_mfma_kernel(
    const float* __restrict__ x, const unsigned short* __restrict__ AdT,
    const unsigned short* __restrict__ Gb, const float* __restrict__ gbias,
    unsigned short* __restrict__ y1Tb, float* __restrict__ part1) {
  __shared__ unsigned short Xs[C_ * 256];     // [c][m] swizzled, 32 KB
  __shared__ unsigned short XAs[256 * C_];    // [n][c] swizzled, 32 KB
  // stats scratch aliased into Xs (dead after pass 1)
  float (*sred)[64] = (float(*)[64])Xs;
  float (*qred)[64] = (float(*)[64])((char*)Xs + 2048);
  int bid = blockIdx.x;
  int b = bid / (T_ / TTG), tile = bid % (T_ / TTG);
  int t0 = tile * TTG;
  int tid = threadIdx.x;

  const float* xsrc = x + (size_t)b * (C_ * PLANE) + (size_t)t0 * J_;
  for (int u = tid; u < C_ * 64; u += 512) {
    int c = u >> 6, qd = u & 63;
    int m = qd * 4;
    float4 v = {0.f, 0.f, 0.f, 0.f};
    if (m < 248) {
      v = *(const float4*)(xsrc + (size_t)c * PLANE + m);
    } else if (m == 248) {
      float2 t2 = *(const float2*)(xsrc + (size_t)c * PLANE + 248);
      v.x = t2.x; v.y = t2.y;
    }
    unsigned p0 = (unsigned)f2bf(v.x) | ((unsigned)f2bf(v.y) << 16);
    unsigned p1 = (unsigned)f2bf(v.z) | ((unsigned)f2bf(v.w) << 16);
    int elem = ((c << 8) | m) ^ ((c & 7) << 3);
    ((unsigned*)Xs)[elem >> 1] = p0;
    ((unsigned*)Xs)[(elem >> 1) + 1] = p1;
  }
  __syncthreads();

  int l = tid & 63, w = tid >> 6;
  int lr = l & 15, lh = l >> 4;
  int n0 = w * 32;

  // ---- pass 1: XA = X * Ad (block-diagonal => narrow q window) ----
  f32x4 acc1[4][2];
#pragma unroll
  for (int mf = 0; mf < 4; ++mf)
#pragma unroll
    for (int nf = 0; nf < 2; ++nf) acc1[mf][nf] = (f32x4)0.f;

  int tlo = n0 / 25, thi = (n0 + 31) / 25;
  int qlw = (tlo * 25) >> 5;
  int qhw = min(7, (thi * 25 + 24) >> 5);
  for (int q = qlw; q <= qhw; ++q) {
    bf16x8 afx[4];
#pragma unroll
    for (int mf = 0; mf < 4; ++mf) {
      int c = mf * 16 + lr;
      int elem = ((c << 8) | (q * 32 + lh * 8)) ^ ((c & 7) << 3);
      afx[mf] = *(const bf16x8*)&Xs[elem];
    }
#pragma unroll
    for (int nf = 0; nf < 2; ++nf) {
      int nbase = n0 + nf * 16;
      int ql = ((nbase / 25) * 25) >> 5;
      int qh = min(7, (((nbase + 15) / 25) * 25 + 24) >> 5);
      if (q < ql || q > qh) continue;
      int n = nbase + lr;
      bf16x8 bfx = *(const bf16x8*)&AdT[n * 256 + q * 32 + lh * 8];
#pragma unroll
      for (int mf = 0; mf < 4; ++mf)
        acc1[mf][nf] = __builtin_amdgcn_mfma_f32_16x16x32_bf16(afx[mf], bfx, acc1[mf][nf], 0, 0, 0);
    }
  }

  // ---- write XA to LDS [n][c] swizzled ----
#pragma unroll
  for (int mf = 0; mf < 4; ++mf) {
    int cb = mf * 16 + 4 * lh;
#pragma unroll
    for (int nf = 0; nf < 2; ++nf) {
      int n = n0 + nf * 16 + lr;
      unsigned p0 = (unsigned)f2bf(acc1[mf][nf][0]) | ((unsigned)f2bf(acc1[mf][nf][1]) << 16);
      unsigned p1 = (unsigned)f2bf(acc1[mf][nf][2]) | ((unsigned)f2bf(acc1[mf][nf][3]) << 16);
      int e0 = ((n << 6) | cb) ^ ((n & 7) << 3);
      ((unsigned*)XAs)[e0 >> 1] = p0;
      ((unsigned*)XAs)[(e0 >> 1) + 1] = p1;
    }
  }
  __syncthreads();

  // ---- pass 2: y1 = Gb * XA + bias ----
  f32x4 acc[4][2];
#pragma unroll
  for (int mf = 0; mf < 4; ++mf)
#pragma unroll
    for (int nf = 0; nf < 2; ++nf) acc[mf][nf] = (f32x4)0.f;

  bf16x8 af[4][2];
#pragma unroll
  for (int mf = 0; mf < 4; ++mf) {
    const unsigned short* wp = Gb + (mf * 16 + lr) * C_ + lh * 8;
    af[mf][0] = *(const bf16x8*)(wp);
    af[mf][1] = *(const bf16x8*)(wp + 32);
  }
  bf16x8 bfr[2][2];
#pragma unroll
  for (int nf = 0; nf < 2; ++nf) {
    int r = n0 + nf * 16 + lr;
    int sw = (r & 7) << 3;
    bfr[nf][0] = *(const bf16x8*)&XAs[((r << 6) | (lh * 8)) ^ sw];
    bfr[nf][1] = *(const bf16x8*)&XAs[((r << 6) | (32 + lh * 8)) ^ sw];
  }
#pragma unroll
  for (int mf = 0; mf < 4; ++mf)
#pragma unroll
    for (int nf = 0; nf < 2; ++nf) {
      acc[mf][nf] = __builtin_amdgcn_mfma_f32_16x16x32_bf16(af[mf][0], bfr[nf][0], acc[mf][nf], 0, 0, 0);
      acc[mf][nf] = __builtin_amdgcn_mfma_f32_16x16x32_bf16(af[mf][1], bfr[nf][1], acc[mf][nf], 0, 0, 0);
    }

  // ---- epilogue: bf16 store to y1T[b][row][c] + fused BN1 partials ----
  unsigned short* ydst = y1Tb + ((size_t)b * PLANE + (size_t)t0 * J_) * C_;
#pragma unroll
  for (int mf = 0; mf < 4; ++mf) {
    float4 gb4 = *(const float4*)(gbias + mf * 16 + 4 * lh);
    float sv[4] = {0.f, 0.f, 0.f, 0.f}, qv[4] = {0.f, 0.f, 0.f, 0.f};
#pragma unroll
    for (int nf = 0; nf < 2; ++nf) {
      int n = n0 + nf * 16 + lr;
      float v0 = acc[mf][nf][0] + gb4.x;
      float v1 = acc[mf][nf][1] + gb4.y;
      float v2 = acc[mf][nf][2] + gb4.z;
      float v3 = acc[mf][nf][3] + gb4.w;
      if (n < 250) {
        unsigned p0 = (unsigned)f2bf(v0) | ((unsigned)f2bf(v1) << 16);
        unsigned p1 = (unsigned)f2bf(v2) | ((unsigned)f2bf(v3) << 16);
        *(uint2*)(ydst + (size_t)n * C_ + mf * 16 + 4 * lh) = make_uint2(p0, p1);
        sv[0] += v0; qv[0] += v0 * v0;
        sv[1] += v1; qv[1] += v1 * v1;
        sv[2] += v2; qv[2] += v2 * v2;
        sv[3] += v3; qv[3] += v3 * v3;
      }
    }
#pragma unroll
    for (int reg = 0; reg < 4; ++reg) {
      float s = sv[reg], q = qv[reg];
#pragma unroll
      for (int m = 1; m < 16; m <<= 1) {
        s += __shfl_xor(s, m);
        q += __shfl_xor(q, m);
      }
      if (lr == 0) {
        int o = mf * 16 + 4 * lh + reg;
        sred[w][o] = s; qred[w][o] = q;
      }
    }
  }
  __syncthreads();
  if (tid < 64) {
    float S = 0.f, Q = 0.f;
#pragma unroll
    for (int i = 0; i < 8; ++i) { S += sred[i][tid]; Q += qred[i][tid]; }
    part1[bid * 128 + tid] = S;
    part1[bid * 128 + 64 + tid] = Q;
  }
}

// ---------------------------------------------------------------------------
// K3: parallel reduce of partials -> BN params.  1024 thr = 16 grp x 64 c.
__global__ __launch_bounds__(1024) void bnparam_reduce_kernel(
    const float* __restrict__ part, int nparts,
    const float* __restrict__ g, const float* __restrict__ b,
    float* __restrict__ bnp) {
  int tid = threadIdx.x;
  int c = tid & 63, grp = tid >> 6;
  float S = 0.f, Q = 0.f;
  for (int k = grp; k < nparts; k += 16) {
    S += part[k * 128 + c];
    Q += part[k * 128 + 64 + c];
  }
  __shared__ float sS[16][64], sQ[16][64];
  sS[grp][c] = S; sQ[grp][c] = Q;
  __syncthreads();
  if (tid < 64) {
    float St = 0.f, Qt = 0.f;
#pragma unroll
    for (int i = 0; i < 16; ++i) { St += sS[i][tid]; Qt += sQ[i][tid]; }
    float mean = St / BN_N;
    float var = Qt / BN_N - mean * mean;
    float inv = rsqrtf(var + BN_EPS);
    float sc = g[tid] * inv;
    bnp[tid] = sc;
    bnp[C_ + tid] = b[tid] - mean * sc;
  }
}

// ---------------------------------------------------------------------------
// K4: MFMA temporal conv, 512 threads. y1T bf16 in, y2 bf16 out.
constexpr int TT = 10;
constexpr int ZROWS_TOT = 456;
__global__ __launch_bounds__(512) void tcn_mfma_kernel(
    const unsigned short* __restrict__ y1Tb, const unsigned short* __restrict__ Wb,
    const float* __restrict__ bnp1, const float* __restrict__ tbias,
    unsigned short* __restrict__ y2b, float* __restrict__ part2) {
  __shared__ unsigned short zs[ZROWS_TOT * C_];   // 58368 B
  __shared__ float sred[8][64], qred[8][64];      // 4 KB
  int bid = blockIdx.x;
  int b = bid / (T_ / TT), tile = bid % (T_ / TT);
  int t0 = tile * TT;
  int tid = threadIdx.x;

  // ---- stage z = relu(bn1(y1T)) bf16, swizzled [row][c] ----
  {
    int cq8 = (tid & 7) * 8, rg = tid >> 3;       // 64 row-groups
    float4 scA = *(const float4*)(bnp1 + cq8);
    float4 scB = *(const float4*)(bnp1 + cq8 + 4);
    float4 shA = *(const float4*)(bnp1 + C_ + cq8);
    float4 shB = *(const float4*)(bnp1 + C_ + cq8 + 4);
    const unsigned short* base = y1Tb + (size_t)b * PLANE * C_;
    int g0 = t0 * J_ - 100;
    for (int rr = rg; rr < 450; rr += 64) {
      int gr = g0 + rr;
      unsigned o0 = 0, o1 = 0, o2 = 0, o3 = 0;
      if (gr >= 0 && gr < PLANE) {
        u16x8 v = *(const u16x8*)(base + (size_t)gr * C_ + cq8);
        float z0 = fmaxf(fmaf(bf2f(v[0]), scA.x, shA.x), 0.f);
        float z1 = fmaxf(fmaf(bf2f(v[1]), scA.y, shA.y), 0.f);
        float z2 = fmaxf(fmaf(bf2f(v[2]), scA.z, shA.z), 0.f);
        float z3 = fmaxf(fmaf(bf2f(v[3]), scA.w, shA.w), 0.f);
        float z4 = fmaxf(fmaf(bf2f(v[4]), scB.x, shB.x), 0.f);
        float z5 = fmaxf(fmaf(bf2f(v[5]), scB.y, shB.y), 0.f);
        float z6 = fmaxf(fmaf(bf2f(v[6]), scB.z, shB.z), 0.f);
        float z7 = fmaxf(fmaf(bf2f(v[7]), scB.w, shB.w), 0.f);
        o0 = (unsigned)f2bf(z0) | ((unsigned)f2bf(z1) << 16);
        o1 = (unsigned)f2bf(z2) | ((unsigned)f2bf(z3) << 16);
        o2 = (unsigned)f2bf(z4) | ((unsigned)f2bf(z5) << 16);
        o3 = (unsigned)f2bf(z6) | ((unsigned)f2bf(z7) << 16);
      }
      int elem = ((rr << 6) | cq8) ^ ((rr & 7) << 3);
      *(uint4*)&zs[elem] = make_uint4(o0, o1, o2, o3);
    }
    for (int u = tid; u < 48; u += 512) {
      int rr = 450 + (u >> 3), cc = (u & 7) * 8;
      int elem = ((rr << 6) | cc) ^ ((rr & 7) << 3);
      *(uint4*)&zs[elem] = make_uint4(0u, 0u, 0u, 0u);
    }
  }
  __syncthreads();

  int l = tid & 63, w = tid >> 6;
  int lr = l & 15, lh = l >> 4;
  int n0 = w * 32;
  f32x4 acc[4][2];
#pragma unroll
  for (int mf = 0; mf < 4; ++mf)
#pragma unroll
    for (int nf = 0; nf < 2; ++nf) acc[mf][nf] = (f32x4)0.f;

#pragma unroll
  for (int kt = 0; kt < K9; ++kt) {
    bf16x8 af[4][2];
#pragma unroll
    for (int mf = 0; mf < 4; ++mf) {
      const unsigned short* wp = Wb + kt * (C_ * C_) + (mf * 16 + lr) * C_ + lh * 8;
      af[mf][0] = *(const bf16x8*)(wp);
      af[mf][1] = *(const bf16x8*)(wp + 32);
    }
    bf16x8 bfr[2][2];
#pragma unroll
    for (int nf = 0; nf < 2; ++nf) {
      int r = n0 + nf * 16 + lr + 25 * kt;
      int sw = (r & 7) << 3;
      bfr[nf][0] = *(const bf16x8*)&zs[((r << 6) | (lh * 8)) ^ sw];
      bfr[nf][1] = *(const bf16x8*)&zs[((r << 6) | (32 + lh * 8)) ^ sw];
    }
#pragma unroll
    for (int mf = 0; mf < 4; ++mf)
#pragma unroll
      for (int nf = 0; nf < 2; ++nf) {
        acc[mf][nf] = __builtin_amdgcn_mfma_f32_16x16x32_bf16(af[mf][0], bfr[nf][0], acc[mf][nf], 0, 0, 0);
        acc[mf][nf] = __builtin_amdgcn_mfma_f32_16x16x32_bf16(af[mf][1], bfr[nf][1], acc[mf][nf], 0, 0, 0);
      }
  }

  // ---- epilogue: bias + bf16 store [b][o][plane] + fused BN2 partials ----
  unsigned short* ydst = y2b + (size_t)b * (C_ * PLANE) + (size_t)t0 * J_;
#pragma unroll
  for (int mf = 0; mf < 4; ++mf) {
    float4 tb4 = *(const float4*)(tbias + mf * 16 + 4 * lh);
    float sv[4] = {0.f, 0.f, 0.f, 0.f}, qv[4] = {0.f, 0.f, 0.f, 0.f};
#pragma unroll
    for (int nf = 0; nf < 2; ++nf) {
      int n = n0 + nf * 16 + lr;
      if (n < 250) {
#pragma unroll
        for (int reg = 0; reg < 4; ++reg) {
          int o = mf * 16 + 4 * lh + reg;
          float v = acc[mf][nf][reg] + ((const float*)&tb4)[reg];
          ydst[(size_t)o * PLANE + n] = f2bf(v);
          sv[reg] += v; qv[reg] += v * v;
        }
      }
    }
#pragma unroll
    for (int reg = 0; reg < 4; ++reg) {
      float s = sv[reg], q = qv[reg];
#pragma unroll
      for (int m = 1; m < 16; m <<= 1) {
        s += __shfl_xor(s, m);
        q += __shfl_xor(q, m);
      }
      if (lr == 0) {
        int o = mf * 16 + 4 * lh + reg;
        sred[w][o] = s; qred[w][o] = q;
      }
    }
  }
  __syncthreads();
  if (tid < 64) {
    float S = 0.f, Q = 0.f;
#pragma unroll
    for (int i = 0; i < 8; ++i) { S += sred[i][tid]; Q += qred[i][tid]; }
    part2[bid * 128 + tid] = S;
    part2[bid * 128 + 64 + tid] = Q;
  }
}

// ---------------------------------------------------------------------------
// K5: out = relu(bn2(y2) + x); y2 bf16, out f32
__global__ __launch_bounds__(256) void final_kernel(const unsigned short* __restrict__ y2b,
                                                    const float* __restrict__ x,
                                                    const float* __restrict__ bnp2,
                                                    float* __restrict__ out) {
  int i = blockIdx.x * 256 + threadIdx.x;
  if (i >= BCTJ / 4) return;
  int c = (i / (PLANE / 4)) & (C_ - 1);
  float sc = bnp2[c], sh = bnp2[C_ + c];
  u16x4 yv = *(const u16x4*)(y2b + (size_t)i * 4);
  float4 xv = ((const float4*)x)[i];
  float4 v;
  v.x = fmaxf(fmaf(bf2f(yv[0]), sc, sh) + xv.x, 0.f);
  v.y = fmaxf(fmaf(bf2f(yv[1]), sc, sh) + xv.y, 0.f);
  v.z = fmaxf(fmaf(bf2f(yv[2]), sc, sh) + xv.z, 0.f);
  v.w = fmaxf(fmaf(bf2f(yv[3]), sc, sh) + xv.w, 0.f);
  ((float4*)out)[i] = v;
}

// ---------------------------------------------------------------------------
extern "C" void kernel_launch(void* const* d_in, const int* in_sizes, int n_in,
                              void* d_out, int out_size, void* d_ws, size_t ws_size,
                              hipStream_t stream) {
  const float* x     = (const float*)d_in[0];
  const float* A     = (const float*)d_in[1];
  const float* gcn_w = (const float*)d_in[2];
  const float* gcn_b = (const float*)d_in[3];
  const float* bn1_g = (const float*)d_in[4];
  const float* bn1_b = (const float*)d_in[5];
  const float* tcn_w = (const float*)d_in[6];
  const float* tcn_b = (const float*)d_in[7];
  const float* bn2_g = (const float*)d_in[8];
  const float* bn2_b = (const float*)d_in[9];
  float* out = (float*)d_out;

  unsigned short* y1Tb = (unsigned short*)d_ws;           // BCTJ bf16 (30.7 MB)
  unsigned short* y2b  = y1Tb + BCTJ;                     // BCTJ bf16 (30.7 MB)
  unsigned short* Wb   = y2b + BCTJ;                      // 36,864 bf16
  unsigned short* Gb   = Wb + C_ * C_ * K9;               // 4,096 bf16
  unsigned short* AdT  = Gb + C_ * C_;                    // 65,536 bf16
  float* part = (float*)(AdT + 256 * 256);                // 960*128 f32 (shared)
  float* bnp  = part + 960 * 128;                         // 256 f32

  int prep_n = C_ * C_ * K9 + C_ * C_ + 256 * 256;
  prep_kernel<<<(prep_n + 255) / 256, 256, 0, stream>>>(tcn_w, gcn_w, A, Wb, Gb, AdT);
  gcn_mfma_kernel<<<B_ * (T_ / TTG), 512, 0, stream>>>(x, AdT, Gb, gcn_b, y1Tb, part);
  bnparam_reduce_kernel<<<1, 1024, 0, stream>>>(part, B_ * (T_ / TTG), bn1_g, bn1_b, bnp);
  tcn_mfma_kernel<<<B_ * (T_ / TT), 512, 0, stream>>>(y1Tb, Wb, bnp, tcn_b, y2b, part);
  bnparam_reduce_kernel<<<1, 1024, 0, stream>>>(part, B_ * (T_ / TT), bn2_g, bn2_b, bnp + 128);
  final_kernel<<<BCTJ / 4 / 256, 256, 0, stream>>>(y2b, x, bnp + 128, out);
}

// Round 8
// 176.652 us; speedup vs baseline: 1.1055x; 1.1055x over previous
//
#include <hip/hip_runtime.h>

#define B_   32
#define C_   64
#define T_   300
#define J_   25
#define K9   9
constexpr int PLANE = T_ * J_;           // 7500
constexpr int BCTJ  = B_ * C_ * PLANE;   // 15,360,000
constexpr float BN_EPS = 1e-5f;
constexpr float BN_N   = (float)(B_ * T_ * J_);  // 240000

typedef __attribute__((ext_vector_type(8))) short bf16x8;
typedef __attribute__((ext_vector_type(4))) float f32x4;
typedef __attribute__((ext_vector_type(8))) unsigned short u16x8;
typedef __attribute__((ext_vector_type(4))) unsigned short u16x4;

__device__ inline unsigned short f2bf(float f) {
  unsigned u = __float_as_uint(f);
  unsigned r = (u + 0x7FFF + ((u >> 16) & 1)) >> 16;
  return (unsigned short)r;
}
__device__ inline float bf2f(unsigned short h) {
  return __uint_as_float(((unsigned)h) << 16);
}

// ---------------------------------------------------------------------------
// K0: weight prep (unchanged).
__global__ __launch_bounds__(256) void prep_kernel(const float* __restrict__ tw,
                                                   const float* __restrict__ gw,
                                                   const float* __restrict__ A,
                                                   unsigned short* __restrict__ Wb,
                                                   unsigned short* __restrict__ Gb,
                                                   unsigned short* __restrict__ AdT) {
  int idx = blockIdx.x * 256 + threadIdx.x;
  if (idx < C_ * C_ * K9) {
    int o = idx / (C_ * K9);
    int rem = idx % (C_ * K9);
    int c = rem / K9, kt = rem % K9;
    Wb[kt * (C_ * C_) + o * C_ + c] = f2bf(tw[idx]);
  } else if (idx < C_ * C_ * K9 + C_ * C_) {
    int i = idx - C_ * C_ * K9;
    Gb[i] = f2bf(gw[i]);
  } else if (idx < C_ * C_ * K9 + C_ * C_ + 256 * 256) {
    int i = idx - (C_ * C_ * K9 + C_ * C_);
    int n = i >> 8, m = i & 255;
    float v = 0.f;
    if (n < 250 && m < 250) {
      if (n / 25 == m / 25) v = A[(m % 25) * 25 + (n % 25)];
    }
    AdT[i] = f2bf(v);
  }
}

// ---------------------------------------------------------------------------
// K1: GCN, 256 threads (4 waves x 64-col tiles), fused BN1 partials,
//     bf16 output y1T[b][row][c].
constexpr int TTG = 10;
__global__ __launch_bounds__(256, 2) void gcn_mfma_kernel(
    const float* __restrict__ x, const unsigned short* __restrict__ AdT,
    const unsigned short* __restrict__ Gb, const float* __restrict__ gbias,
    unsigned short* __restrict__ y1Tb, float* __restrict__ part1) {
  __shared__ unsigned short Xs[C_ * 256];     // [c][m] swizzled, 32 KB
  __shared__ unsigned short XAs[256 * C_];    // [n][c] swizzled, 32 KB
  float (*sred)[64] = (float(*)[64])Xs;       // aliased (Xs dead after pass 1)
  float (*qred)[64] = (float(*)[64])((char*)Xs + 1024);
  int bid = blockIdx.x;
  int b = bid / (T_ / TTG), tile = bid % (T_ / TTG);
  int t0 = tile * TTG;
  int tid = threadIdx.x;

  const float* xsrc = x + (size_t)b * (C_ * PLANE) + (size_t)t0 * J_;
  for (int u = tid; u < C_ * 64; u += 256) {
    int c = u >> 6, qd = u & 63;
    int m = qd * 4;
    float4 v = {0.f, 0.f, 0.f, 0.f};
    if (m < 248) {
      v = *(const float4*)(xsrc + (size_t)c * PLANE + m);
    } else if (m == 248) {
      float2 t2 = *(const float2*)(xsrc + (size_t)c * PLANE + 248);
      v.x = t2.x; v.y = t2.y;
    }
    unsigned p0 = (unsigned)f2bf(v.x) | ((unsigned)f2bf(v.y) << 16);
    unsigned p1 = (unsigned)f2bf(v.z) | ((unsigned)f2bf(v.w) << 16);
    int elem = ((c << 8) | m) ^ ((c & 7) << 3);
    ((unsigned*)Xs)[elem >> 1] = p0;
    ((unsigned*)Xs)[(elem >> 1) + 1] = p1;
  }
  __syncthreads();

  int l = tid & 63, w = tid >> 6;
  int lr = l & 15, lh = l >> 4;
  int n0 = w * 64;

  // ---- pass 1: XA = X * Ad (block-diagonal => skip zero K-chunks) ----
  f32x4 acc1[4][4];
#pragma unroll
  for (int mf = 0; mf < 4; ++mf)
#pragma unroll
    for (int nf = 0; nf < 4; ++nf) acc1[mf][nf] = (f32x4)0.f;

  int qminw = ((n0 / 25) * 25) >> 5;
  int qmaxw = min(7, ((((n0 + 63) / 25) + 1) * 25 - 1) >> 5);
  for (int q = qminw; q <= qmaxw; ++q) {
    bf16x8 afx[4];
#pragma unroll
    for (int mf = 0; mf < 4; ++mf) {
      int c = mf * 16 + lr;
      int elem = ((c << 8) | (q * 32 + lh * 8)) ^ ((c & 7) << 3);
      afx[mf] = *(const bf16x8*)&Xs[elem];
    }
#pragma unroll
    for (int nf = 0; nf < 4; ++nf) {
      int nbase = n0 + nf * 16;
      int ql = ((nbase / 25) * 25) >> 5;
      int qh = min(7, ((((nbase + 15) / 25) + 1) * 25 - 1) >> 5);
      if (q < ql || q > qh) continue;
      int n = nbase + lr;
      bf16x8 bfx = *(const bf16x8*)&AdT[n * 256 + q * 32 + lh * 8];
#pragma unroll
      for (int mf = 0; mf < 4; ++mf)
        acc1[mf][nf] = __builtin_amdgcn_mfma_f32_16x16x32_bf16(afx[mf], bfx, acc1[mf][nf], 0, 0, 0);
    }
  }

  // ---- write XA to LDS [n][c] swizzled ----
#pragma unroll
  for (int mf = 0; mf < 4; ++mf) {
    int cb = mf * 16 + 4 * lh;
#pragma unroll
    for (int nf = 0; nf < 4; ++nf) {
      int n = n0 + nf * 16 + lr;
      unsigned p0 = (unsigned)f2bf(acc1[mf][nf][0]) | ((unsigned)f2bf(acc1[mf][nf][1]) << 16);
      unsigned p1 = (unsigned)f2bf(acc1[mf][nf][2]) | ((unsigned)f2bf(acc1[mf][nf][3]) << 16);
      int e0 = ((n << 6) | cb) ^ ((n & 7) << 3);
      ((unsigned*)XAs)[e0 >> 1] = p0;
      ((unsigned*)XAs)[(e0 >> 1) + 1] = p1;
    }
  }
  __syncthreads();

  // ---- pass 2: y1 = Gb * XA + bias ----
  f32x4 acc[4][4];
#pragma unroll
  for (int mf = 0; mf < 4; ++mf)
#pragma unroll
    for (int nf = 0; nf < 4; ++nf) acc[mf][nf] = (f32x4)0.f;

  bf16x8 af[4][2];
#pragma unroll
  for (int mf = 0; mf < 4; ++mf) {
    const unsigned short* wp = Gb + (mf * 16 + lr) * C_ + lh * 8;
    af[mf][0] = *(const bf16x8*)(wp);
    af[mf][1] = *(const bf16x8*)(wp + 32);
  }
  bf16x8 bfr[4][2];
#pragma unroll
  for (int nf = 0; nf < 4; ++nf) {
    int r = n0 + nf * 16 + lr;
    int sw = (r & 7) << 3;
    bfr[nf][0] = *(const bf16x8*)&XAs[((r << 6) | (lh * 8)) ^ sw];
    bfr[nf][1] = *(const bf16x8*)&XAs[((r << 6) | (32 + lh * 8)) ^ sw];
  }
#pragma unroll
  for (int mf = 0; mf < 4; ++mf)
#pragma unroll
    for (int nf = 0; nf < 4; ++nf) {
      acc[mf][nf] = __builtin_amdgcn_mfma_f32_16x16x32_bf16(af[mf][0], bfr[nf][0], acc[mf][nf], 0, 0, 0);
      acc[mf][nf] = __builtin_amdgcn_mfma_f32_16x16x32_bf16(af[mf][1], bfr[nf][1], acc[mf][nf], 0, 0, 0);
    }

  // ---- epilogue: bf16 store + fused BN1 partials ----
  unsigned short* ydst = y1Tb + ((size_t)b * PLANE + (size_t)t0 * J_) * C_;
#pragma unroll
  for (int mf = 0; mf < 4; ++mf) {
    float4 gb4 = *(const float4*)(gbias + mf * 16 + 4 * lh);
    float sv[4] = {0.f, 0.f, 0.f, 0.f}, qv[4] = {0.f, 0.f, 0.f, 0.f};
#pragma unroll
    for (int nf = 0; nf < 4; ++nf) {
      int n = n0 + nf * 16 + lr;
      float v0 = acc[mf][nf][0] + gb4.x;
      float v1 = acc[mf][nf][1] + gb4.y;
      float v2 = acc[mf][nf][2] + gb4.z;
      float v3 = acc[mf][nf][3] + gb4.w;
      if (n < 250) {
        unsigned p0 = (unsigned)f2bf(v0) | ((unsigned)f2bf(v1) << 16);
        unsigned p1 = (unsigned)f2bf(v2) | ((unsigned)f2bf(v3) << 16);
        *(uint2*)(ydst + (size_t)n * C_ + mf * 16 + 4 * lh) = make_uint2(p0, p1);
        sv[0] += v0; qv[0] += v0 * v0;
        sv[1] += v1; qv[1] += v1 * v1;
        sv[2] += v2; qv[2] += v2 * v2;
        sv[3] += v3; qv[3] += v3 * v3;
      }
    }
#pragma unroll
    for (int reg = 0; reg < 4; ++reg) {
      float s = sv[reg], q = qv[reg];
#pragma unroll
      for (int m = 1; m < 16; m <<= 1) {
        s += __shfl_xor(s, m);
        q += __shfl_xor(q, m);
      }
      if (lr == 0) {
        int o = mf * 16 + 4 * lh + reg;
        sred[w][o] = s; qred[w][o] = q;
      }
    }
  }
  __syncthreads();
  if (tid < 64) {
    float S = 0.f, Q = 0.f;
#pragma unroll
    for (int i = 0; i < 4; ++i) { S += sred[i][tid]; Q += qred[i][tid]; }
    part1[bid * 128 + tid] = S;
    part1[bid * 128 + 64 + tid] = Q;
  }
}

// ---------------------------------------------------------------------------
// K3: parallel reduce of partials -> BN params.
__global__ __launch_bounds__(1024) void bnparam_reduce_kernel(
    const float* __restrict__ part, int nparts,
    const float* __restrict__ g, const float* __restrict__ b,
    float* __restrict__ bnp) {
  int tid = threadIdx.x;
  int c = tid & 63, grp = tid >> 6;
  float S = 0.f, Q = 0.f;
  for (int k = grp; k < nparts; k += 16) {
    S += part[k * 128 + c];
    Q += part[k * 128 + 64 + c];
  }
  __shared__ float sS[16][64], sQ[16][64];
  sS[grp][c] = S; sQ[grp][c] = Q;
  __syncthreads();
  if (tid < 64) {
    float St = 0.f, Qt = 0.f;
#pragma unroll
    for (int i = 0; i < 16; ++i) { St += sS[i][tid]; Qt += sQ[i][tid]; }
    float mean = St / BN_N;
    float var = Qt / BN_N - mean * mean;
    float inv = rsqrtf(var + BN_EPS);
    float sc = g[tid] * inv;
    bnp[tid] = sc;
    bnp[C_ + tid] = b[tid] - mean * sc;
  }
}

// ---------------------------------------------------------------------------
// K4: MFMA temporal conv, 256 threads, acc[4][4], register-double-buffered
//     weight A-frags.  bf16 in (y1T) / bf16 out (y2).
constexpr int TT = 10;
constexpr int ZROWS_TOT = 456;
__global__ __launch_bounds__(256, 2) void tcn_mfma_kernel(
    const unsigned short* __restrict__ y1Tb, const unsigned short* __restrict__ Wb,
    const float* __restrict__ bnp1, const float* __restrict__ tbias,
    unsigned short* __restrict__ y2b, float* __restrict__ part2) {
  __shared__ unsigned short zs[ZROWS_TOT * C_];   // 58368 B
  __shared__ float sred[4][64], qred[4][64];      // 2 KB
  int bid = blockIdx.x;
  int b = bid / (T_ / TT), tile = bid % (T_ / TT);
  int t0 = tile * TT;
  int tid = threadIdx.x;

  // ---- stage z = relu(bn1(y1T)) bf16, swizzled [row][c], conflict-free ----
  {
    int cq8 = (tid & 7) * 8, rg = tid >> 3;       // 32 row-groups
    float4 scA = *(const float4*)(bnp1 + cq8);
    float4 scB = *(const float4*)(bnp1 + cq8 + 4);
    float4 shA = *(const float4*)(bnp1 + C_ + cq8);
    float4 shB = *(const float4*)(bnp1 + C_ + cq8 + 4);
    const unsigned short* base = y1Tb + (size_t)b * PLANE * C_;
    int g0 = t0 * J_ - 100;
    for (int rr = rg; rr < 450; rr += 32) {
      int gr = g0 + rr;
      unsigned o0 = 0, o1 = 0, o2 = 0, o3 = 0;
      if (gr >= 0 && gr < PLANE) {
        u16x8 v = *(const u16x8*)(base + (size_t)gr * C_ + cq8);
        float z0 = fmaxf(fmaf(bf2f(v[0]), scA.x, shA.x), 0.f);
        float z1 = fmaxf(fmaf(bf2f(v[1]), scA.y, shA.y), 0.f);
        float z2 = fmaxf(fmaf(bf2f(v[2]), scA.z, shA.z), 0.f);
        float z3 = fmaxf(fmaf(bf2f(v[3]), scA.w, shA.w), 0.f);
        float z4 = fmaxf(fmaf(bf2f(v[4]), scB.x, shB.x), 0.f);
        float z5 = fmaxf(fmaf(bf2f(v[5]), scB.y, shB.y), 0.f);
        float z6 = fmaxf(fmaf(bf2f(v[6]), scB.z, shB.z), 0.f);
        float z7 = fmaxf(fmaf(bf2f(v[7]), scB.w, shB.w), 0.f);
        o0 = (unsigned)f2bf(z0) | ((unsigned)f2bf(z1) << 16);
        o1 = (unsigned)f2bf(z2) | ((unsigned)f2bf(z3) << 16);
        o2 = (unsigned)f2bf(z4) | ((unsigned)f2bf(z5) << 16);
        o3 = (unsigned)f2bf(z6) | ((unsigned)f2bf(z7) << 16);
      }
      int elem = ((rr << 6) | cq8) ^ ((rr & 7) << 3);
      *(uint4*)&zs[elem] = make_uint4(o0, o1, o2, o3);
    }
    for (int u = tid; u < 48; u += 256) {
      int rr = 450 + (u >> 3), cc = (u & 7) * 8;
      int elem = ((rr << 6) | cc) ^ ((rr & 7) << 3);
      *(uint4*)&zs[elem] = make_uint4(0u, 0u, 0u, 0u);
    }
  }
  __syncthreads();

  int l = tid & 63, w = tid >> 6;
  int lr = l & 15, lh = l >> 4;
  int n0 = w * 64;
  f32x4 acc[4][4];
#pragma unroll
  for (int mf = 0; mf < 4; ++mf)
#pragma unroll
    for (int nf = 0; nf < 4; ++nf) acc[mf][nf] = (f32x4)0.f;

  // preload kt=0 weight A-frags
  bf16x8 afc[4][2];
#pragma unroll
  for (int mf = 0; mf < 4; ++mf) {
    const unsigned short* wp = Wb + (mf * 16 + lr) * C_ + lh * 8;
    afc[mf][0] = *(const bf16x8*)(wp);
    afc[mf][1] = *(const bf16x8*)(wp + 32);
  }

#pragma unroll
  for (int kt = 0; kt < K9; ++kt) {
    bf16x8 afn[4][2];
    if (kt < K9 - 1) {            // prefetch next kt's weights (hidden by MFMAs)
#pragma unroll
      for (int mf = 0; mf < 4; ++mf) {
        const unsigned short* wp = Wb + (kt + 1) * (C_ * C_) + (mf * 16 + lr) * C_ + lh * 8;
        afn[mf][0] = *(const bf16x8*)(wp);
        afn[mf][1] = *(const bf16x8*)(wp + 32);
      }
    }
    bf16x8 bfr[4][2];
#pragma unroll
    for (int nf = 0; nf < 4; ++nf) {
      int r = n0 + nf * 16 + lr + 25 * kt;
      int sw = (r & 7) << 3;
      bfr[nf][0] = *(const bf16x8*)&zs[((r << 6) | (lh * 8)) ^ sw];
      bfr[nf][1] = *(const bf16x8*)&zs[((r << 6) | (32 + lh * 8)) ^ sw];
    }
#pragma unroll
    for (int mf = 0; mf < 4; ++mf)
#pragma unroll
      for (int nf = 0; nf < 4; ++nf) {
        acc[mf][nf] = __builtin_amdgcn_mfma_f32_16x16x32_bf16(afc[mf][0], bfr[nf][0], acc[mf][nf], 0, 0, 0);
        acc[mf][nf] = __builtin_amdgcn_mfma_f32_16x16x32_bf16(afc[mf][1], bfr[nf][1], acc[mf][nf], 0, 0, 0);
      }
    if (kt < K9 - 1) {
#pragma unroll
      for (int mf = 0; mf < 4; ++mf) {
        afc[mf][0] = afn[mf][0];
        afc[mf][1] = afn[mf][1];
      }
    }
  }

  // ---- epilogue: bias + bf16 store [b][o][plane] + fused BN2 partials ----
  unsigned short* ydst = y2b + (size_t)b * (C_ * PLANE) + (size_t)t0 * J_;
#pragma unroll
  for (int mf = 0; mf < 4; ++mf) {
    float4 tb4 = *(const float4*)(tbias + mf * 16 + 4 * lh);
    float sv[4] = {0.f, 0.f, 0.f, 0.f}, qv[4] = {0.f, 0.f, 0.f, 0.f};
#pragma unroll
    for (int nf = 0; nf < 4; ++nf) {
      int n = n0 + nf * 16 + lr;
      if (n < 250) {
#pragma unroll
        for (int reg = 0; reg < 4; ++reg) {
          int o = mf * 16 + 4 * lh + reg;
          float v = acc[mf][nf][reg] + ((const float*)&tb4)[reg];
          ydst[(size_t)o * PLANE + n] = f2bf(v);
          sv[reg] += v; qv[reg] += v * v;
        }
      }
    }
#pragma unroll
    for (int reg = 0; reg < 4; ++reg) {
      float s = sv[reg], q = qv[reg];
#pragma unroll
      for (int m = 1; m < 16; m <<= 1) {
        s += __shfl_xor(s, m);
        q += __shfl_xor(q, m);
      }
      if (lr == 0) {
        int o = mf * 16 + 4 * lh + reg;
        sred[w][o] = s; qred[w][o] = q;
      }
    }
  }
  __syncthreads();
  if (tid < 64) {
    float S = 0.f, Q = 0.f;
#pragma unroll
    for (int i = 0; i < 4; ++i) { S += sred[i][tid]; Q += qred[i][tid]; }
    part2[bid * 128 + tid] = S;
    part2[bid * 128 + 64 + tid] = Q;
  }
}

// ---------------------------------------------------------------------------
// K5: out = relu(bn2(y2) + x); y2 bf16, out f32
__global__ __launch_bounds__(256) void final_kernel(const unsigned short* __restrict__ y2b,
                                                    const float* __restrict__ x,
                                                    const float* __restrict__ bnp2,
                                                    float* __restrict__ out) {
  int i = blockIdx.x * 256 + threadIdx.x;
  if (i >= BCTJ / 4) return;
  int c = (i / (PLANE / 4)) & (C_ - 1);
  float sc = bnp2[c], sh = bnp2[C_ + c];
  u16x4 yv = *(const u16x4*)(y2b + (size_t)i * 4);
  float4 xv = ((const float4*)x)[i];
  float4 v;
  v.x = fmaxf(fmaf(bf2f(yv[0]), sc, sh) + xv.x, 0.f);
  v.y = fmaxf(fmaf(bf2f(yv[1]), sc, sh) + xv.y, 0.f);
  v.z = fmaxf(fmaf(bf2f(yv[2]), sc, sh) + xv.z, 0.f);
  v.w = fmaxf(fmaf(bf2f(yv[3]), sc, sh) + xv.w, 0.f);
  ((float4*)out)[i] = v;
}

// ---------------------------------------------------------------------------
extern "C" void kernel_launch(void* const* d_in, const int* in_sizes, int n_in,
                              void* d_out, int out_size, void* d_ws, size_t ws_size,
                              hipStream_t stream) {
  const float* x     = (const float*)d_in[0];
  const float* A     = (const float*)d_in[1];
  const float* gcn_w = (const float*)d_in[2];
  const float* gcn_b = (const float*)d_in[3];
  const float* bn1_g = (const float*)d_in[4];
  const float* bn1_b = (const float*)d_in[5];
  const float* tcn_w = (const float*)d_in[6];
  const float* tcn_b = (const float*)d_in[7];
  const float* bn2_g = (const float*)d_in[8];
  const float* bn2_b = (const float*)d_in[9];
  float* out = (float*)d_out;

  unsigned short* y1Tb = (unsigned short*)d_ws;           // BCTJ bf16 (30.7 MB)
  unsigned short* y2b  = y1Tb + BCTJ;                     // BCTJ bf16 (30.7 MB)
  unsigned short* Wb   = y2b + BCTJ;                      // 36,864 bf16
  unsigned short* Gb   = Wb + C_ * C_ * K9;               // 4,096 bf16
  unsigned short* AdT  = Gb + C_ * C_;                    // 65,536 bf16
  float* part = (float*)(AdT + 256 * 256);                // 960*128 f32 (shared)
  float* bnp  = part + 960 * 128;                         // 256 f32

  int prep_n = C_ * C_ * K9 + C_ * C_ + 256 * 256;
  prep_kernel<<<(prep_n + 255) / 256, 256, 0, stream>>>(tcn_w, gcn_w, A, Wb, Gb, AdT);
  gcn_mfma_kernel<<<B_ * (T_ / TTG), 256, 0, stream>>>(x, AdT, Gb, gcn_b, y1Tb, part);
  bnparam_reduce_kernel<<<1, 1024, 0, stream>>>(part, B_ * (T_ / TTG), bn1_g, bn1_b, bnp);
  tcn_mfma_kernel<<<B_ * (T_ / TT), 256, 0, stream>>>(y1Tb, Wb, bnp, tcn_b, y2b, part);
  bnparam_reduce_kernel<<<1, 1024, 0, stream>>>(part, B_ * (T_ / TT), bn2_g, bn2_b, bnp + 128);
  final_kernel<<<BCTJ / 4 / 256, 256, 0, stream>>>(y2b, x, bnp + 128, out);
}

// Round 9
// 151.778 us; speedup vs baseline: 1.2867x; 1.1639x over previous
//
#include <hip/hip_runtime.h>

#define B_   32
#define C_   64
#define T_   300
#define J_   25
#define K9   9
constexpr int PLANE = T_ * J_;           // 7500
constexpr int BCTJ  = B_ * C_ * PLANE;   // 15,360,000
constexpr float BN_EPS = 1e-5f;
constexpr float BN_N   = (float)(B_ * T_ * J_);  // 240000

typedef __attribute__((ext_vector_type(8))) short bf16x8;
typedef __attribute__((ext_vector_type(4))) float f32x4;
typedef __attribute__((ext_vector_type(8))) unsigned short u16x8;
typedef __attribute__((ext_vector_type(4))) unsigned short u16x4;

__device__ inline unsigned short f2bf(float f) {
  unsigned u = __float_as_uint(f);
  unsigned r = (u + 0x7FFF + ((u >> 16) & 1)) >> 16;
  return (unsigned short)r;
}
__device__ inline float bf2f(unsigned short h) {
  return __uint_as_float(((unsigned)h) << 16);
}

// ---------------------------------------------------------------------------
// K0: weight prep (unchanged).
__global__ __launch_bounds__(256) void prep_kernel(const float* __restrict__ tw,
                                                   const float* __restrict__ gw,
                                                   const float* __restrict__ A,
                                                   unsigned short* __restrict__ Wb,
                                                   unsigned short* __restrict__ Gb,
                                                   unsigned short* __restrict__ AdT) {
  int idx = blockIdx.x * 256 + threadIdx.x;
  if (idx < C_ * C_ * K9) {
    int o = idx / (C_ * K9);
    int rem = idx % (C_ * K9);
    int c = rem / K9, kt = rem % K9;
    Wb[kt * (C_ * C_) + o * C_ + c] = f2bf(tw[idx]);
  } else if (idx < C_ * C_ * K9 + C_ * C_) {
    int i = idx - C_ * C_ * K9;
    Gb[i] = f2bf(gw[i]);
  } else if (idx < C_ * C_ * K9 + C_ * C_ + 256 * 256) {
    int i = idx - (C_ * C_ * K9 + C_ * C_);
    int n = i >> 8, m = i & 255;
    float v = 0.f;
    if (n < 250 && m < 250) {
      if (n / 25 == m / 25) v = A[(m % 25) * 25 + (n % 25)];
    }
    AdT[i] = f2bf(v);
  }
}

// ---------------------------------------------------------------------------
// K1: GCN. 256 thr, 4 blocks/CU. One 32KB LDS buffer aliased X -> XA -> outT.
//  Batched staging loads; coalesced transposed output store; fused BN1 stats.
constexpr int TTG = 10;
__global__ __launch_bounds__(256, 4) void gcn_mfma_kernel(
    const float* __restrict__ x, const unsigned short* __restrict__ AdT,
    const unsigned short* __restrict__ Gb, const float* __restrict__ gbias,
    unsigned short* __restrict__ y1Tb, float* __restrict__ part1) {
  __shared__ unsigned short Xs[C_ * 256];     // 32 KB, triple-aliased
  __shared__ float sred[4][64], qred[4][64];  // 2 KB
  int bid = blockIdx.x;
  int b = bid / (T_ / TTG), tile = bid % (T_ / TTG);
  int t0 = tile * TTG;
  int tid = threadIdx.x;

  // ---- stage x tile bf16 [c][m] swizzled; 16 batched unconditional loads ----
  {
    size_t sbase = (size_t)b * (C_ * PLANE) + (size_t)t0 * J_;
    int c0 = tid >> 6;           // 0..3
    int m  = (tid & 63) * 4;     // 0..252
    float4 vb[16];
#pragma unroll
    for (int k = 0; k < 16; ++k) {
      size_t off = sbase + (size_t)(c0 + 4 * k) * PLANE + m;
      if (off > (size_t)(BCTJ - 4)) off = (size_t)(BCTJ - 4);  // clamp edge OOB
      vb[k] = *(const float4*)(x + off);
    }
    // cols >=250 may be garbage -> multiplied by AdT zero rows, harmless
#pragma unroll
    for (int k = 0; k < 16; ++k) {
      int c = c0 + 4 * k;
      unsigned p0 = (unsigned)f2bf(vb[k].x) | ((unsigned)f2bf(vb[k].y) << 16);
      unsigned p1 = (unsigned)f2bf(vb[k].z) | ((unsigned)f2bf(vb[k].w) << 16);
      int elem = ((c << 8) | m) ^ ((c & 7) << 3);
      *(uint2*)&Xs[elem] = make_uint2(p0, p1);
    }
  }
  __syncthreads();

  int l = tid & 63, w = tid >> 6;
  int lr = l & 15, lh = l >> 4;
  int n0 = w * 64;

  // ---- pass 1: XA = X * Ad (block-diagonal => skip zero K-chunks) ----
  f32x4 acc1[4][4];
#pragma unroll
  for (int mf = 0; mf < 4; ++mf)
#pragma unroll
    for (int nf = 0; nf < 4; ++nf) acc1[mf][nf] = (f32x4)0.f;

  int qminw = ((n0 / 25) * 25) >> 5;
  int qmaxw = min(7, ((((n0 + 63) / 25) + 1) * 25 - 1) >> 5);
  for (int q = qminw; q <= qmaxw; ++q) {
    bf16x8 afx[4];
#pragma unroll
    for (int mf = 0; mf < 4; ++mf) {
      int c = mf * 16 + lr;
      int elem = ((c << 8) | (q * 32 + lh * 8)) ^ ((c & 7) << 3);
      afx[mf] = *(const bf16x8*)&Xs[elem];
    }
#pragma unroll
    for (int nf = 0; nf < 4; ++nf) {
      int nbase = n0 + nf * 16;
      int ql = ((nbase / 25) * 25) >> 5;
      int qh = min(7, ((((nbase + 15) / 25) + 1) * 25 - 1) >> 5);
      if (q < ql || q > qh) continue;
      int n = nbase + lr;
      bf16x8 bfx = *(const bf16x8*)&AdT[n * 256 + q * 32 + lh * 8];
#pragma unroll
      for (int mf = 0; mf < 4; ++mf)
        acc1[mf][nf] = __builtin_amdgcn_mfma_f32_16x16x32_bf16(afx[mf], bfx, acc1[mf][nf], 0, 0, 0);
    }
  }
  __syncthreads();   // all waves done reading X before overwrite

  // ---- write XA into same buffer, [n][c] swizzled ----
#pragma unroll
  for (int mf = 0; mf < 4; ++mf) {
    int cb = mf * 16 + 4 * lh;
#pragma unroll
    for (int nf = 0; nf < 4; ++nf) {
      int n = n0 + nf * 16 + lr;
      unsigned p0 = (unsigned)f2bf(acc1[mf][nf][0]) | ((unsigned)f2bf(acc1[mf][nf][1]) << 16);
      unsigned p1 = (unsigned)f2bf(acc1[mf][nf][2]) | ((unsigned)f2bf(acc1[mf][nf][3]) << 16);
      int e0 = ((n << 6) | cb) ^ ((n & 7) << 3);
      *(uint2*)&Xs[e0] = make_uint2(p0, p1);
    }
  }
  __syncthreads();

  // ---- pass 2: y1 = Gb * XA + bias ----
  f32x4 acc[4][4];
#pragma unroll
  for (int mf = 0; mf < 4; ++mf)
#pragma unroll
    for (int nf = 0; nf < 4; ++nf) acc[mf][nf] = (f32x4)0.f;

  bf16x8 af[4][2];
#pragma unroll
  for (int mf = 0; mf < 4; ++mf) {
    const unsigned short* wp = Gb + (mf * 16 + lr) * C_ + lh * 8;
    af[mf][0] = *(const bf16x8*)(wp);
    af[mf][1] = *(const bf16x8*)(wp + 32);
  }
  bf16x8 bfr[4][2];
#pragma unroll
  for (int nf = 0; nf < 4; ++nf) {
    int r = n0 + nf * 16 + lr;
    int sw = (r & 7) << 3;
    bfr[nf][0] = *(const bf16x8*)&Xs[((r << 6) | (lh * 8)) ^ sw];
    bfr[nf][1] = *(const bf16x8*)&Xs[((r << 6) | (32 + lh * 8)) ^ sw];
  }
#pragma unroll
  for (int mf = 0; mf < 4; ++mf)
#pragma unroll
    for (int nf = 0; nf < 4; ++nf) {
      acc[mf][nf] = __builtin_amdgcn_mfma_f32_16x16x32_bf16(af[mf][0], bfr[nf][0], acc[mf][nf], 0, 0, 0);
      acc[mf][nf] = __builtin_amdgcn_mfma_f32_16x16x32_bf16(af[mf][1], bfr[nf][1], acc[mf][nf], 0, 0, 0);
    }
  __syncthreads();   // all waves done reading XA before overwrite

  // ---- epilogue: stats + bf16 transpose into LDS [n][c] ----
#pragma unroll
  for (int mf = 0; mf < 4; ++mf) {
    float4 gb4 = *(const float4*)(gbias + mf * 16 + 4 * lh);
    int cb = mf * 16 + 4 * lh;
    float sv[4] = {0.f, 0.f, 0.f, 0.f}, qv[4] = {0.f, 0.f, 0.f, 0.f};
#pragma unroll
    for (int nf = 0; nf < 4; ++nf) {
      int n = n0 + nf * 16 + lr;
      float v0 = acc[mf][nf][0] + gb4.x;
      float v1 = acc[mf][nf][1] + gb4.y;
      float v2 = acc[mf][nf][2] + gb4.z;
      float v3 = acc[mf][nf][3] + gb4.w;
      if (n < 250) {
        sv[0] += v0; qv[0] += v0 * v0;
        sv[1] += v1; qv[1] += v1 * v1;
        sv[2] += v2; qv[2] += v2 * v2;
        sv[3] += v3; qv[3] += v3 * v3;
      }
      unsigned p0 = (unsigned)f2bf(v0) | ((unsigned)f2bf(v1) << 16);
      unsigned p1 = (unsigned)f2bf(v2) | ((unsigned)f2bf(v3) << 16);
      int e0 = ((n << 6) | cb) ^ ((n & 7) << 3);
      *(uint2*)&Xs[e0] = make_uint2(p0, p1);
    }
#pragma unroll
    for (int reg = 0; reg < 4; ++reg) {
      float s = sv[reg], q = qv[reg];
#pragma unroll
      for (int m = 1; m < 16; m <<= 1) {
        s += __shfl_xor(s, m);
        q += __shfl_xor(q, m);
      }
      if (lr == 0) {
        int o = mf * 16 + 4 * lh + reg;
        sred[w][o] = s; qred[w][o] = q;
      }
    }
  }
  __syncthreads();

  // ---- coalesced store: 8 lanes/row, 128B contiguous rows ----
  unsigned short* ydst = y1Tb + ((size_t)b * PLANE + (size_t)t0 * J_) * C_;
#pragma unroll
  for (int it = 0; it < 8; ++it) {
    int task = it * 256 + tid;
    int n = task >> 3, ch = task & 7;
    if (n < 250) {
      int e = ((n << 6) | (ch * 8)) ^ ((n & 7) << 3);
      u16x8 v = *(const u16x8*)&Xs[e];
      *(u16x8*)(ydst + (size_t)n * C_ + ch * 8) = v;
    }
  }
  if (tid < 64) {
    float S = 0.f, Q = 0.f;
#pragma unroll
    for (int i = 0; i < 4; ++i) { S += sred[i][tid]; Q += qred[i][tid]; }
    part1[bid * 128 + tid] = S;
    part1[bid * 128 + 64 + tid] = Q;
  }
}

// ---------------------------------------------------------------------------
// K3: parallel reduce of partials -> BN params.
__global__ __launch_bounds__(1024) void bnparam_reduce_kernel(
    const float* __restrict__ part, int nparts,
    const float* __restrict__ g, const float* __restrict__ b,
    float* __restrict__ bnp) {
  int tid = threadIdx.x;
  int c = tid & 63, grp = tid >> 6;
  float S = 0.f, Q = 0.f;
  for (int k = grp; k < nparts; k += 16) {
    S += part[k * 128 + c];
    Q += part[k * 128 + 64 + c];
  }
  __shared__ float sS[16][64], sQ[16][64];
  sS[grp][c] = S; sQ[grp][c] = Q;
  __syncthreads();
  if (tid < 64) {
    float St = 0.f, Qt = 0.f;
#pragma unroll
    for (int i = 0; i < 16; ++i) { St += sS[i][tid]; Qt += sQ[i][tid]; }
    float mean = St / BN_N;
    float var = Qt / BN_N - mean * mean;
    float inv = rsqrtf(var + BN_EPS);
    float sc = g[tid] * inv;
    bnp[tid] = sc;
    bnp[C_ + tid] = b[tid] - mean * sc;
  }
}

// ---------------------------------------------------------------------------
// K4: TCN. Batched staging (480-row zs, fixed 15 iters), weight prefetch,
//     LDS [o][260] transpose epilogue -> coalesced dword stores.
constexpr int TT = 10;
constexpr int ZROWS_TOT = 480;             // 450 data + 30 pad (mult of 32)
__global__ __launch_bounds__(256, 2) void tcn_mfma_kernel(
    const unsigned short* __restrict__ y1Tb, const unsigned short* __restrict__ Wb,
    const float* __restrict__ bnp1, const float* __restrict__ tbias,
    unsigned short* __restrict__ y2b, float* __restrict__ part2) {
  __shared__ unsigned short zs[ZROWS_TOT * C_];   // 61440 B; reused as [o][260]
  __shared__ float sred[4][64], qred[4][64];      // 2 KB
  unsigned short* zs2 = zs;                       // alias, 64*260*2 = 33.3 KB
  int bid = blockIdx.x;
  int b = bid / (T_ / TT), tile = bid % (T_ / TT);
  int t0 = tile * TT;
  int tid = threadIdx.x;

  // ---- stage z = relu(bn1(y1T)) bf16 swizzled [row][c]; 15 batched loads ----
  {
    int cq8 = (tid & 7) * 8, rg = tid >> 3;       // rg 0..31
    float4 scA = *(const float4*)(bnp1 + cq8);
    float4 scB = *(const float4*)(bnp1 + cq8 + 4);
    float4 shA = *(const float4*)(bnp1 + C_ + cq8);
    float4 shB = *(const float4*)(bnp1 + C_ + cq8 + 4);
    const unsigned short* base = y1Tb + (size_t)b * PLANE * C_;
    int g0 = t0 * J_ - 100;
    u16x8 vb[15];
#pragma unroll
    for (int k = 0; k < 15; ++k) {
      int gr = g0 + rg + 32 * k;
      int gc = min(max(gr, 0), PLANE - 1);        // clamp, mask later
      vb[k] = *(const u16x8*)(base + (size_t)gc * C_ + cq8);
    }
#pragma unroll
    for (int k = 0; k < 15; ++k) {
      int rr = rg + 32 * k;
      int gr = g0 + rr;
      bool valid = (gr >= 0) && (gr < PLANE);
      u16x8 v = vb[k];
      float z0 = valid ? fmaxf(fmaf(bf2f(v[0]), scA.x, shA.x), 0.f) : 0.f;
      float z1 = valid ? fmaxf(fmaf(bf2f(v[1]), scA.y, shA.y), 0.f) : 0.f;
      float z2 = valid ? fmaxf(fmaf(bf2f(v[2]), scA.z, shA.z), 0.f) : 0.f;
      float z3 = valid ? fmaxf(fmaf(bf2f(v[3]), scA.w, shA.w), 0.f) : 0.f;
      float z4 = valid ? fmaxf(fmaf(bf2f(v[4]), scB.x, shB.x), 0.f) : 0.f;
      float z5 = valid ? fmaxf(fmaf(bf2f(v[5]), scB.y, shB.y), 0.f) : 0.f;
      float z6 = valid ? fmaxf(fmaf(bf2f(v[6]), scB.z, shB.z), 0.f) : 0.f;
      float z7 = valid ? fmaxf(fmaf(bf2f(v[7]), scB.w, shB.w), 0.f) : 0.f;
      unsigned o0 = (unsigned)f2bf(z0) | ((unsigned)f2bf(z1) << 16);
      unsigned o1 = (unsigned)f2bf(z2) | ((unsigned)f2bf(z3) << 16);
      unsigned o2 = (unsigned)f2bf(z4) | ((unsigned)f2bf(z5) << 16);
      unsigned o3 = (unsigned)f2bf(z6) | ((unsigned)f2bf(z7) << 16);
      int elem = ((rr << 6) | cq8) ^ ((rr & 7) << 3);
      *(uint4*)&zs[elem] = make_uint4(o0, o1, o2, o3);
    }
  }
  __syncthreads();

  int l = tid & 63, w = tid >> 6;
  int lr = l & 15, lh = l >> 4;
  int n0 = w * 64;
  f32x4 acc[4][4];
#pragma unroll
  for (int mf = 0; mf < 4; ++mf)
#pragma unroll
    for (int nf = 0; nf < 4; ++nf) acc[mf][nf] = (f32x4)0.f;

  bf16x8 afc[4][2];
#pragma unroll
  for (int mf = 0; mf < 4; ++mf) {
    const unsigned short* wp = Wb + (mf * 16 + lr) * C_ + lh * 8;
    afc[mf][0] = *(const bf16x8*)(wp);
    afc[mf][1] = *(const bf16x8*)(wp + 32);
  }

#pragma unroll
  for (int kt = 0; kt < K9; ++kt) {
    bf16x8 afn[4][2];
    if (kt < K9 - 1) {
#pragma unroll
      for (int mf = 0; mf < 4; ++mf) {
        const unsigned short* wp = Wb + (kt + 1) * (C_ * C_) + (mf * 16 + lr) * C_ + lh * 8;
        afn[mf][0] = *(const bf16x8*)(wp);
        afn[mf][1] = *(const bf16x8*)(wp + 32);
      }
    }
    bf16x8 bfr[4][2];
#pragma unroll
    for (int nf = 0; nf < 4; ++nf) {
      int r = n0 + nf * 16 + lr + 25 * kt;
      int sw = (r & 7) << 3;
      bfr[nf][0] = *(const bf16x8*)&zs[((r << 6) | (lh * 8)) ^ sw];
      bfr[nf][1] = *(const bf16x8*)&zs[((r << 6) | (32 + lh * 8)) ^ sw];
    }
#pragma unroll
    for (int mf = 0; mf < 4; ++mf)
#pragma unroll
      for (int nf = 0; nf < 4; ++nf) {
        acc[mf][nf] = __builtin_amdgcn_mfma_f32_16x16x32_bf16(afc[mf][0], bfr[nf][0], acc[mf][nf], 0, 0, 0);
        acc[mf][nf] = __builtin_amdgcn_mfma_f32_16x16x32_bf16(afc[mf][1], bfr[nf][1], acc[mf][nf], 0, 0, 0);
      }
    if (kt < K9 - 1) {
#pragma unroll
      for (int mf = 0; mf < 4; ++mf) {
        afc[mf][0] = afn[mf][0];
        afc[mf][1] = afn[mf][1];
      }
    }
  }
  __syncthreads();   // all waves done reading zs before zs2 overwrite

  // ---- epilogue: stats + bf16 transpose into LDS [o][260] ----
#pragma unroll
  for (int mf = 0; mf < 4; ++mf) {
    float4 tb4 = *(const float4*)(tbias + mf * 16 + 4 * lh);
    float sv[4] = {0.f, 0.f, 0.f, 0.f}, qv[4] = {0.f, 0.f, 0.f, 0.f};
#pragma unroll
    for (int nf = 0; nf < 4; ++nf) {
      int n = n0 + nf * 16 + lr;
      if (n < 250) {
#pragma unroll
        for (int reg = 0; reg < 4; ++reg) {
          int o = mf * 16 + 4 * lh + reg;
          float v = acc[mf][nf][reg] + ((const float*)&tb4)[reg];
          zs2[o * 260 + n] = f2bf(v);
          sv[reg] += v; qv[reg] += v * v;
        }
      }
    }
#pragma unroll
    for (int reg = 0; reg < 4; ++reg) {
      float s = sv[reg], q = qv[reg];
#pragma unroll
      for (int m = 1; m < 16; m <<= 1) {
        s += __shfl_xor(s, m);
        q += __shfl_xor(q, m);
      }
      if (lr == 0) {
        int o = mf * 16 + 4 * lh + reg;
        sred[w][o] = s; qred[w][o] = q;
      }
    }
  }
  __syncthreads();

  // ---- coalesced store: dword (2 n) granularity, [o][plane] ----
  unsigned short* ydst = y2b + (size_t)b * (C_ * PLANE) + (size_t)t0 * J_;
#pragma unroll
  for (int it = 0; it < 32; ++it) {
    int task = it * 256 + tid;
    if (task < 8000) {
      int o = task / 125;
      int k = task - o * 125;
      unsigned d = *(const unsigned*)&zs2[o * 260 + 2 * k];
      *(unsigned*)(ydst + (size_t)o * PLANE + 2 * k) = d;
    }
  }
  if (tid < 64) {
    float S = 0.f, Q = 0.f;
#pragma unroll
    for (int i = 0; i < 4; ++i) { S += sred[i][tid]; Q += qred[i][tid]; }
    part2[bid * 128 + tid] = S;
    part2[bid * 128 + 64 + tid] = Q;
  }
}

// ---------------------------------------------------------------------------
// K5: out = relu(bn2(y2) + x); y2 bf16, out f32
__global__ __launch_bounds__(256) void final_kernel(const unsigned short* __restrict__ y2b,
                                                    const float* __restrict__ x,
                                                    const float* __restrict__ bnp2,
                                                    float* __restrict__ out) {
  int i = blockIdx.x * 256 + threadIdx.x;
  if (i >= BCTJ / 4) return;
  int c = (i / (PLANE / 4)) & (C_ - 1);
  float sc = bnp2[c], sh = bnp2[C_ + c];
  u16x4 yv = *(const u16x4*)(y2b + (size_t)i * 4);
  float4 xv = ((const float4*)x)[i];
  float4 v;
  v.x = fmaxf(fmaf(bf2f(yv[0]), sc, sh) + xv.x, 0.f);
  v.y = fmaxf(fmaf(bf2f(yv[1]), sc, sh) + xv.y, 0.f);
  v.z = fmaxf(fmaf(bf2f(yv[2]), sc, sh) + xv.z, 0.f);
  v.w = fmaxf(fmaf(bf2f(yv[3]), sc, sh) + xv.w, 0.f);
  ((float4*)out)[i] = v;
}

// ---------------------------------------------------------------------------
extern "C" void kernel_launch(void* const* d_in, const int* in_sizes, int n_in,
                              void* d_out, int out_size, void* d_ws, size_t ws_size,
                              hipStream_t stream) {
  const float* x     = (const float*)d_in[0];
  const float* A     = (const float*)d_in[1];
  const float* gcn_w = (const float*)d_in[2];
  const float* gcn_b = (const float*)d_in[3];
  const float* bn1_g = (const float*)d_in[4];
  const float* bn1_b = (const float*)d_in[5];
  const float* tcn_w = (const float*)d_in[6];
  const float* tcn_b = (const float*)d_in[7];
  const float* bn2_g = (const float*)d_in[8];
  const float* bn2_b = (const float*)d_in[9];
  float* out = (float*)d_out;

  unsigned short* y1Tb = (unsigned short*)d_ws;           // BCTJ bf16
  unsigned short* y2b  = y1Tb + BCTJ;                     // BCTJ bf16
  unsigned short* Wb   = y2b + BCTJ;                      // 36,864 bf16
  unsigned short* Gb   = Wb + C_ * C_ * K9;               // 4,096 bf16
  unsigned short* AdT  = Gb + C_ * C_;                    // 65,536 bf16
  float* part = (float*)(AdT + 256 * 256);                // 960*128 f32
  float* bnp  = part + 960 * 128;                         // 256 f32

  int prep_n = C_ * C_ * K9 + C_ * C_ + 256 * 256;
  prep_kernel<<<(prep_n + 255) / 256, 256, 0, stream>>>(tcn_w, gcn_w, A, Wb, Gb, AdT);
  gcn_mfma_kernel<<<B_ * (T_ / TTG), 256, 0, stream>>>(x, AdT, Gb, gcn_b, y1Tb, part);
  bnparam_reduce_kernel<<<1, 1024, 0, stream>>>(part, B_ * (T_ / TTG), bn1_g, bn1_b, bnp);
  tcn_mfma_kernel<<<B_ * (T_ / TT), 256, 0, stream>>>(y1Tb, Wb, bnp, tcn_b, y2b, part);
  bnparam_reduce_kernel<<<1, 1024, 0, stream>>>(part, B_ * (T_ / TT), bn2_g, bn2_b, bnp + 128);
  final_kernel<<<BCTJ / 4 / 256, 256, 0, stream>>>(y2b, x, bnp + 128, out);
}